// Round 11
// baseline (449.339 us; speedup 1.0000x reference)
//
#include <hip/hip_runtime.h>
#include <cstdint>
#include <cstddef>

#define NN 8192
#define HEADS 4

typedef __attribute__((ext_vector_type(4))) float  f4;
typedef __attribute__((ext_vector_type(4))) int    i4;
typedef __attribute__((ext_vector_type(8))) short  short8;
typedef __attribute__((ext_vector_type(4))) unsigned int   u4;
typedef unsigned int   uint32;

__device__ __forceinline__ unsigned short f2bf(float f) {
    unsigned int u = __builtin_bit_cast(unsigned int, f);
    u += 0x7FFFu + ((u >> 16) & 1u);           // RNE
    return (unsigned short)(u >> 16);
}

// ---------------- K0: W -> WT bf16 (transposed) ---------------------------
__global__ __launch_bounds__(256) void k0_convert(const float* __restrict__ W,
                                                  unsigned short* __restrict__ WT) {
    int f = blockIdx.x;                 // 0..255 : input-feature row of W
    int c = threadIdx.x;                // 0..255 : (head*64+d) column
    WT[c * 256 + f] = f2bf(W[f * 256 + c]);
}

// load 8 consecutive f32 and convert to bf16 (RNE)
__device__ __forceinline__ short8 ld8bf(const float* __restrict__ p) {
    f4 lo = *(const f4*)p;
    f4 hi = *(const f4*)(p + 4);
    short8 r;
    r[0] = f2bf(lo.x); r[1] = f2bf(lo.y); r[2] = f2bf(lo.z); r[3] = f2bf(lo.w);
    r[4] = f2bf(hi.x); r[5] = f2bf(hi.y); r[6] = f2bf(hi.z); r[7] = f2bf(hi.w);
    return r;
}

// ---------------- K1: h = x*W (bf16 MFMA) -> hF (B-frag order) + exp tables
__global__ __launch_bounds__(256) void k1_hgemm(
    const float* __restrict__ x, const unsigned short* __restrict__ WT,
    const float* __restrict__ aS, const float* __restrict__ aD,
    unsigned short* __restrict__ hF,
    float* __restrict__ sE, float* __restrict__ sE2,
    float* __restrict__ dE, float* __restrict__ dE2)
{
    const int tid  = threadIdx.x;
    const int head = tid >> 6;
    const int lane = tid & 63;
    const int col  = lane & 15;
    const int quad = lane >> 4;
    const int i0   = blockIdx.x * 32;

    const float* ar0 = x + (size_t)(i0 + col) * 256 + quad * 8;
    const float* ar1 = ar0 + 16 * 256;
    const unsigned short* br = WT + (size_t)(head * 64 + col) * 256 + quad * 8;

    f4 C[2][4];
    #pragma unroll
    for (int a = 0; a < 2; a++)
        #pragma unroll
        for (int b = 0; b < 4; b++) C[a][b] = f4{0.f, 0.f, 0.f, 0.f};

    #pragma unroll
    for (int kk = 0; kk < 256; kk += 32) {
        short8 a0 = ld8bf(ar0 + kk);
        short8 a1 = ld8bf(ar1 + kk);
        #pragma unroll
        for (int nt = 0; nt < 4; nt++) {
            short8 bf = *(const short8*)(br + nt * 16 * 256 + kk);
            C[0][nt] = __builtin_amdgcn_mfma_f32_16x16x32_bf16(a0, bf, C[0][nt], 0, 0, 0);
            C[1][nt] = __builtin_amdgcn_mfma_f32_16x16x32_bf16(a1, bf, C[1][nt], 0, 0, 0);
        }
    }

    // ---- src/dst logit exps ----------------------------------------------
    float as_[4], ad_[4];
    #pragma unroll
    for (int nt = 0; nt < 4; nt++) {
        as_[nt] = aS[head * 64 + nt * 16 + col];
        ad_[nt] = aD[head * 64 + nt * 16 + col];
    }
    #pragma unroll
    for (int mt = 0; mt < 2; mt++) {
        #pragma unroll
        for (int r = 0; r < 4; r++) {
            float sv = 0.f, dv = 0.f;
            #pragma unroll
            for (int nt = 0; nt < 4; nt++) {
                sv += C[mt][nt][r] * as_[nt];
                dv += C[mt][nt][r] * ad_[nt];
            }
            #pragma unroll
            for (int m = 1; m < 16; m <<= 1) {     // reduce over the 16 cols
                sv += __shfl_xor(sv, m, 64);
                dv += __shfl_xor(dv, m, 64);
            }
            if (col == 0) {
                int i = i0 + mt * 16 + quad * 4 + r;
                float zs = sv * 1.4426950408889634f;   // log2(e) folded
                float zd = dv * 1.4426950408889634f;
                sE [head * NN + i] = __builtin_amdgcn_exp2f(zs);
                sE2[head * NN + i] = __builtin_amdgcn_exp2f(0.2f * zs);
                dE [head * NN + i] = __builtin_amdgcn_exp2f(zd);
                dE2[head * NN + i] = __builtin_amdgcn_exp2f(0.2f * zd);
            }
        }
    }

    // ---- hF scatter into B-fragment order --------------------------------
    const size_t fbase = (((size_t)blockIdx.x * HEADS + head) * 4) * 512;
    #pragma unroll
    for (int mt = 0; mt < 2; mt++) {
        #pragma unroll
        for (int nt = 0; nt < 4; nt++) {
            #pragma unroll
            for (int r = 0; r < 4; r++) {
                int il = mt * 16 + quad * 4 + r;      // j-local 0..31
                int qp = il >> 3;
                int t  = il & 7;
                hF[fbase + (size_t)nt * 512 + (qp * 16 + col) * 8 + t] =
                    f2bf(C[mt][nt][r]);
            }
        }
    }
}

// ---------------- K2: fused pack + masked softmax-weight + aggregation ----
// Proven round-0 bit path: mf = (float)((bits>>t)&1), +0x8000/v_perm pack.
__device__ __forceinline__ short8 build_w(uint32 bits,
                                          const f4& alo, const f4& ahi,
                                          const f4& blo, const f4& bhi,
                                          float es, float es2) {
    float aa[8] = {alo[0], alo[1], alo[2], alo[3], ahi[0], ahi[1], ahi[2], ahi[3]};
    float bb[8] = {blo[0], blo[1], blo[2], blo[3], bhi[0], bhi[1], bhi[2], bhi[3]};
    float e[8];
    #pragma unroll
    for (int t = 0; t < 8; t++) {
        float av = es  * aa[t];
        float bv = es2 * bb[t];
        float m  = fmaxf(av, bv);                 // exp2(leaky) via monotonicity
        float mf = (float)((bits >> t) & 1u);
        e[t] = m * mf;
    }
    u4 pv;
    #pragma unroll
    for (int t = 0; t < 4; t++) {
        uint32 e0 = __builtin_bit_cast(uint32, e[2 * t])     + 0x8000u;
        uint32 e1 = __builtin_bit_cast(uint32, e[2 * t + 1]) + 0x8000u;
        pv[t] = __builtin_amdgcn_perm(e1, e0, 0x07060302u);  // [hi16(e1):hi16(e0)]
    }
    return __builtin_bit_cast(short8, pv);
}

// grid = 128 i-tiles (64 rows) * jsplit; block = 256 thr (wave = head).
// 64-row tile doubles the MFMA work amortized over each B-frag/dE load
// (r7 established the intensity slope: 16-row=200us, 32-row=148us).
// Register budget: acc 80 + st 32 + ~70 temps ~ 180 VGPR < 256 cap at
// __launch_bounds__(256,2) -- no spill (r6 lesson).
// split = blockIdx & (jsplit-1): XCD round-robin -> each XCD owns one split.
__global__ __launch_bounds__(256, 2) void k2_gat(
    const int* __restrict__ adj, const unsigned short* __restrict__ hF,
    const float* __restrict__ sE, const float* __restrict__ sE2,
    const float* __restrict__ dE, const float* __restrict__ dE2,
    float* __restrict__ Pout, float* __restrict__ PS,
    int jshift, int jchunk)
{
    const int tid   = threadIdx.x;
    const int head  = tid >> 6;
    const int lane  = tid & 63;
    const int col   = lane & 15;
    const int quad  = lane >> 4;
    const int split = blockIdx.x & ((1 << jshift) - 1);
    const int itile = blockIdx.x >> jshift;
    const int i0    = itile * 64;
    const int j0    = split * jchunk;

    __shared__ uint32 abits[2][64][4];    // [buf][row 0..63][32-j word]

    float es_[4], esb_[4];
    #pragma unroll
    for (int mt = 0; mt < 4; mt++) {
        es_[mt]  = sE [head * NN + i0 + mt * 16 + col];
        esb_[mt] = sE2[head * NN + i0 + mt * 16 + col];
    }

    const float* dEp  = dE  + head * NN + j0 + quad * 8;
    const float* dE2p = dE2 + head * NN + j0 + quad * 8;
    const unsigned short* hbase =
        hF + ((size_t)(j0 >> 5) * HEADS + head) * 4 * 512 + lane * 8;

    // wave (=head) stages rows head*16 .. head*16+15 of this 64-row tile
    const int* abase = adj + (size_t)(i0 + head * 16) * NN + j0 + lane;

    f4 acc[4][4];
    f4 accS[4];
    #pragma unroll
    for (int a = 0; a < 4; a++) {
        accS[a] = f4{0.f, 0.f, 0.f, 0.f};
        #pragma unroll
        for (int b = 0; b < 4; b++) acc[a][b] = f4{0.f, 0.f, 0.f, 0.f};
    }
    short8 ones;
    #pragma unroll
    for (int t = 0; t < 8; t++) ones[t] = (short)0x3F80;   // bf16 1.0

    const int ngrp = jchunk >> 7;             // groups of 128 j (4 jb)

    int st[32];                               // staged raw adj (static idx only)
    auto issue = [&](int g) {
        #pragma unroll
        for (int r = 0; r < 16; ++r) {
            const int* rp = abase + (size_t)r * NN + g * 128;
            st[2 * r]     = rp[0];            // j = g*128 + lane
            st[2 * r + 1] = rp[64];           // j = g*128 + 64 + lane
        }
    };
    auto commit = [&](int buf) {
        #pragma unroll
        for (int r = 0; r < 16; ++r) {
            unsigned long long m0 = __ballot(st[2 * r]     != 0);
            unsigned long long m1 = __ballot(st[2 * r + 1] != 0);
            if (lane == 0) {
                abits[buf][head * 16 + r][0] = (uint32)m0;
                abits[buf][head * 16 + r][1] = (uint32)(m0 >> 32);
                abits[buf][head * 16 + r][2] = (uint32)m1;
                abits[buf][head * 16 + r][3] = (uint32)(m1 >> 32);
            }
        }
    };

    issue(0);
    commit(0);
    __syncthreads();

    for (int g = 0; g < ngrp; ++g) {
        const int cur = g & 1;
        if (g + 1 < ngrp) issue(g + 1);       // overlap HBM latency w/ compute

        #pragma unroll
        for (int k = 0; k < 4; ++k) {
            const int jb = g * 4 + k;         // local 32-j block
            const float* dp  = dEp  + jb * 32;
            const float* dp2 = dE2p + jb * 32;
            f4 alo = *(const f4*)(dp);
            f4 ahi = *(const f4*)(dp + 4);
            f4 blo = *(const f4*)(dp2);
            f4 bhi = *(const f4*)(dp2 + 4);
            const unsigned short* hp = hbase + (size_t)jb * (HEADS * 4 * 512);
            short8 B0 = *(const short8*)(hp);
            short8 B1 = *(const short8*)(hp + 512);
            short8 B2 = *(const short8*)(hp + 1024);
            short8 B3 = *(const short8*)(hp + 1536);

            #pragma unroll
            for (int mt = 0; mt < 4; mt++) {
                uint32 w = abits[cur][mt * 16 + col][k];
                uint32 b = (w >> (quad * 8)) & 0xFFu;
                short8 af = build_w(b, alo, ahi, blo, bhi, es_[mt], esb_[mt]);
                acc[mt][0] = __builtin_amdgcn_mfma_f32_16x16x32_bf16(af, B0, acc[mt][0], 0, 0, 0);
                acc[mt][1] = __builtin_amdgcn_mfma_f32_16x16x32_bf16(af, B1, acc[mt][1], 0, 0, 0);
                acc[mt][2] = __builtin_amdgcn_mfma_f32_16x16x32_bf16(af, B2, acc[mt][2], 0, 0, 0);
                acc[mt][3] = __builtin_amdgcn_mfma_f32_16x16x32_bf16(af, B3, acc[mt][3], 0, 0, 0);
                accS[mt]   = __builtin_amdgcn_mfma_f32_16x16x32_bf16(af, ones, accS[mt], 0, 0, 0);
            }
        }

        if (g + 1 < ngrp) commit(cur ^ 1);
        __syncthreads();
    }

    // ---- store partials ---------------------------------------------------
    #pragma unroll
    for (int mt = 0; mt < 4; mt++) {
        #pragma unroll
        for (int nt = 0; nt < 4; nt++) {
            #pragma unroll
            for (int r = 0; r < 4; r++) {
                int row = i0 + mt * 16 + quad * 4 + r;
                Pout[((size_t)split * NN + row) * 256 + head * 64 + nt * 16 + col] =
                    acc[mt][nt][r];
            }
        }
        if (col == 0) {
            #pragma unroll
            for (int r = 0; r < 4; r++) {
                int row = i0 + mt * 16 + quad * 4 + r;
                PS[((size_t)split * NN + row) * HEADS + head] = accS[mt][r];
            }
        }
    }
}

// ---------------- K3: reduce splits, normalize, add bias ------------------
__global__ void k3_norm(const float* __restrict__ Pout, const float* __restrict__ PS,
                        const float* __restrict__ bias, float* __restrict__ out,
                        int jsplit)
{
    int t  = blockIdx.x * 256 + threadIdx.x;   // 0..524287
    int c4 = t * 4;
    int i    = c4 >> 8;
    int cb   = c4 & 255;
    int head = cb >> 6;
    f4 num = f4{0.f, 0.f, 0.f, 0.f};
    float den = 0.f;
    for (int s = 0; s < jsplit; s++) {
        num += *(const f4*)(Pout + ((size_t)s * NN + i) * 256 + cb);
        den += PS[((size_t)s * NN + i) * HEADS + head];
    }
    f4 bv = *(const f4*)(bias + cb);
    f4 o  = num * (1.0f / den) + bv;
    *(f4*)(out + c4) = o;
}

extern "C" void kernel_launch(void* const* d_in, const int* in_sizes, int n_in,
                              void* d_out, int out_size, void* d_ws, size_t ws_size,
                              hipStream_t stream) {
    (void)in_sizes; (void)n_in; (void)out_size;
    const float* x    = (const float*)d_in[0];
    const int*   adj  = (const int*)d_in[1];
    const float* W    = (const float*)d_in[2];
    const float* aS   = (const float*)d_in[3];
    const float* aD   = (const float*)d_in[4];
    const float* bias = (const float*)d_in[5];
    float* out = (float*)d_out;

    char* ws = (char*)d_ws;
    unsigned short* WT = (unsigned short*)(ws);              //  128 KB
    unsigned short* hF = (unsigned short*)(ws +   131072);   //  4 MB
    float*  sE   = (float*)(ws +  4325376);                  //  128 KB
    float*  sE2  = (float*)(ws +  4456448);                  //  128 KB
    float*  dE   = (float*)(ws +  4587520);                  //  128 KB
    float*  dE2  = (float*)(ws +  4718592);                  //  128 KB
    float*  PS   = (float*)(ws +  4849664);                  //  up to 1 MB
    float*  Pout = (float*)(ws +  5898240);                  //  jsplit * 8 MB

    const size_t need8 = 5898240ull + 8ull * 8388608ull;
    const int jsplit = (ws_size >= need8) ? 8 : 4;
    const int jshift = (jsplit == 8) ? 3 : 2;
    const int jchunk = NN / jsplit;

    k0_convert<<<256, 256, 0, stream>>>(W, WT);
    k1_hgemm<<<256, 256, 0, stream>>>(x, WT, aS, aD, hF, sE, sE2, dE, dE2);
    k2_gat<<<128 * jsplit, 256, 0, stream>>>(adj, hF, sE, sE2, dE, dE2, Pout, PS, jshift, jchunk);
    k3_norm<<<2048, 256, 0, stream>>>(Pout, PS, bias, out, jsplit);
}

// Round 12
// 435.068 us; speedup vs baseline: 1.0328x; 1.0328x over previous
//
#include <hip/hip_runtime.h>
#include <cstdint>
#include <cstddef>

#define NN 8192
#define HEADS 4

typedef __attribute__((ext_vector_type(4))) float  f4;
typedef __attribute__((ext_vector_type(4))) int    i4;
typedef __attribute__((ext_vector_type(8))) short  short8;
typedef __attribute__((ext_vector_type(4))) unsigned int   u4;
typedef unsigned int   uint32;

__device__ __forceinline__ unsigned short f2bf(float f) {
    unsigned int u = __builtin_bit_cast(unsigned int, f);
    u += 0x7FFFu + ((u >> 16) & 1u);           // RNE
    return (unsigned short)(u >> 16);
}

// ---------------- K0: W -> WT bf16 (transposed) ---------------------------
__global__ __launch_bounds__(256) void k0_convert(const float* __restrict__ W,
                                                  unsigned short* __restrict__ WT) {
    int f = blockIdx.x;                 // 0..255 : input-feature row of W
    int c = threadIdx.x;                // 0..255 : (head*64+d) column
    WT[c * 256 + f] = f2bf(W[f * 256 + c]);
}

// load 8 consecutive f32 and convert to bf16 (RNE)
__device__ __forceinline__ short8 ld8bf(const float* __restrict__ p) {
    f4 lo = *(const f4*)p;
    f4 hi = *(const f4*)(p + 4);
    short8 r;
    r[0] = f2bf(lo.x); r[1] = f2bf(lo.y); r[2] = f2bf(lo.z); r[3] = f2bf(lo.w);
    r[4] = f2bf(hi.x); r[5] = f2bf(hi.y); r[6] = f2bf(hi.z); r[7] = f2bf(hi.w);
    return r;
}

// ---------------- K1: h = x*W (bf16 MFMA) -> hF (B-frag order) + exp tables
__global__ __launch_bounds__(256) void k1_hgemm(
    const float* __restrict__ x, const unsigned short* __restrict__ WT,
    const float* __restrict__ aS, const float* __restrict__ aD,
    unsigned short* __restrict__ hF,
    float* __restrict__ sE, float* __restrict__ sE2,
    float* __restrict__ dE, float* __restrict__ dE2)
{
    const int tid  = threadIdx.x;
    const int head = tid >> 6;
    const int lane = tid & 63;
    const int col  = lane & 15;
    const int quad = lane >> 4;
    const int i0   = blockIdx.x * 32;

    const float* ar0 = x + (size_t)(i0 + col) * 256 + quad * 8;
    const float* ar1 = ar0 + 16 * 256;
    const unsigned short* br = WT + (size_t)(head * 64 + col) * 256 + quad * 8;

    f4 C[2][4];
    #pragma unroll
    for (int a = 0; a < 2; a++)
        #pragma unroll
        for (int b = 0; b < 4; b++) C[a][b] = f4{0.f, 0.f, 0.f, 0.f};

    #pragma unroll
    for (int kk = 0; kk < 256; kk += 32) {
        short8 a0 = ld8bf(ar0 + kk);
        short8 a1 = ld8bf(ar1 + kk);
        #pragma unroll
        for (int nt = 0; nt < 4; nt++) {
            short8 bf = *(const short8*)(br + nt * 16 * 256 + kk);
            C[0][nt] = __builtin_amdgcn_mfma_f32_16x16x32_bf16(a0, bf, C[0][nt], 0, 0, 0);
            C[1][nt] = __builtin_amdgcn_mfma_f32_16x16x32_bf16(a1, bf, C[1][nt], 0, 0, 0);
        }
    }

    // ---- src/dst logit exps ----------------------------------------------
    float as_[4], ad_[4];
    #pragma unroll
    for (int nt = 0; nt < 4; nt++) {
        as_[nt] = aS[head * 64 + nt * 16 + col];
        ad_[nt] = aD[head * 64 + nt * 16 + col];
    }
    #pragma unroll
    for (int mt = 0; mt < 2; mt++) {
        #pragma unroll
        for (int r = 0; r < 4; r++) {
            float sv = 0.f, dv = 0.f;
            #pragma unroll
            for (int nt = 0; nt < 4; nt++) {
                sv += C[mt][nt][r] * as_[nt];
                dv += C[mt][nt][r] * ad_[nt];
            }
            #pragma unroll
            for (int m = 1; m < 16; m <<= 1) {     // reduce over the 16 cols
                sv += __shfl_xor(sv, m, 64);
                dv += __shfl_xor(dv, m, 64);
            }
            if (col == 0) {
                int i = i0 + mt * 16 + quad * 4 + r;
                float zs = sv * 1.4426950408889634f;   // log2(e) folded
                float zd = dv * 1.4426950408889634f;
                sE [head * NN + i] = __builtin_amdgcn_exp2f(zs);
                sE2[head * NN + i] = __builtin_amdgcn_exp2f(0.2f * zs);
                dE [head * NN + i] = __builtin_amdgcn_exp2f(zd);
                dE2[head * NN + i] = __builtin_amdgcn_exp2f(0.2f * zd);
            }
        }
    }

    // ---- hF scatter into B-fragment order --------------------------------
    const size_t fbase = (((size_t)blockIdx.x * HEADS + head) * 4) * 512;
    #pragma unroll
    for (int mt = 0; mt < 2; mt++) {
        #pragma unroll
        for (int nt = 0; nt < 4; nt++) {
            #pragma unroll
            for (int r = 0; r < 4; r++) {
                int il = mt * 16 + quad * 4 + r;      // j-local 0..31
                int qp = il >> 3;
                int t  = il & 7;
                hF[fbase + (size_t)nt * 512 + (qp * 16 + col) * 8 + t] =
                    f2bf(C[mt][nt][r]);
            }
        }
    }
}

// ---------------- K2: fused pack + masked softmax-weight + aggregation ----
// Proven round-0 bit path: mf = (float)((bits>>t)&1), +0x8000/v_perm pack.
__device__ __forceinline__ short8 build_w(uint32 bits,
                                          const f4& alo, const f4& ahi,
                                          const f4& blo, const f4& bhi,
                                          float es, float es2) {
    float aa[8] = {alo[0], alo[1], alo[2], alo[3], ahi[0], ahi[1], ahi[2], ahi[3]};
    float bb[8] = {blo[0], blo[1], blo[2], blo[3], bhi[0], bhi[1], bhi[2], bhi[3]};
    float e[8];
    #pragma unroll
    for (int t = 0; t < 8; t++) {
        float av = es  * aa[t];
        float bv = es2 * bb[t];
        float m  = fmaxf(av, bv);                 // exp2(leaky) via monotonicity
        float mf = (float)((bits >> t) & 1u);
        e[t] = m * mf;
    }
    u4 pv;
    #pragma unroll
    for (int t = 0; t < 4; t++) {
        uint32 e0 = __builtin_bit_cast(uint32, e[2 * t])     + 0x8000u;
        uint32 e1 = __builtin_bit_cast(uint32, e[2 * t + 1]) + 0x8000u;
        pv[t] = __builtin_amdgcn_perm(e1, e0, 0x07060302u);  // [hi16(e1):hi16(e0)]
    }
    return __builtin_bit_cast(short8, pv);
}

// grid = 256 i-tiles * jsplit; block = 256 thr (wave = head). r4 structure +
// global_load_lds double-buffered B-frag pipeline:
//  - bfB[2][head][4KB]: next jb's 4 B-frags stream HBM/L2->LDS async (dest is
//    wave-uniform base + lane*16B == our lane*8-short fragment layout).
//  - counted s_waitcnt vmcnt(N) per k (never 0 mid-group): drains only the
//    current jb's 4 loads; adj prefetch (16, issued k==0) + next-B stay in
//    flight. N derived from in-order vmcnt semantics with issue order pinned
//    by sched_barrier(0): {24,24,8,8}; last group uses vmcnt(0) (safe drain).
//  - arithmetic/order bit-identical to r4 (absmax must be 0.001953125).
__global__ __launch_bounds__(256, 4) void k2_gat(
    const int* __restrict__ adj, const unsigned short* __restrict__ hF,
    const float* __restrict__ sE, const float* __restrict__ sE2,
    const float* __restrict__ dE, const float* __restrict__ dE2,
    float* __restrict__ Pout, float* __restrict__ PS,
    int jshift, int jchunk)
{
    const int tid   = threadIdx.x;
    const int head  = tid >> 6;
    const int lane  = tid & 63;
    const int col   = lane & 15;
    const int quad  = lane >> 4;
    const int split = blockIdx.x & ((1 << jshift) - 1);
    const int itile = blockIdx.x >> jshift;
    const int i0    = itile * 32;
    const int j0    = split * jchunk;

    __shared__ uint32 abits[2][32][4];                       // 1 KB
    __shared__ __align__(16) unsigned short bfB[2][HEADS][2048]; // 32 KB

    const float es0  = sE [head * NN + i0 + col];
    const float es0b = sE2[head * NN + i0 + col];
    const float es1  = sE [head * NN + i0 + 16 + col];
    const float es1b = sE2[head * NN + i0 + 16 + col];

    const float* dEp  = dE  + head * NN + j0 + quad * 8;
    const float* dE2p = dE2 + head * NN + j0 + quad * 8;
    const unsigned short* hbase =
        hF + ((size_t)(j0 >> 5) * HEADS + head) * 4 * 512 + lane * 8;

    // wave (=head) stages rows head*8 .. head*8+7 of this block's 32-row tile
    const int* abase = adj + (size_t)(i0 + head * 8) * NN + j0 + lane;

    f4 acc[2][4];
    f4 accS[2];
    #pragma unroll
    for (int a = 0; a < 2; a++) {
        accS[a] = f4{0.f, 0.f, 0.f, 0.f};
        #pragma unroll
        for (int b = 0; b < 4; b++) acc[a][b] = f4{0.f, 0.f, 0.f, 0.f};
    }
    short8 ones;
    #pragma unroll
    for (int t = 0; t < 8; t++) ones[t] = (short)0x3F80;   // bf16 1.0

    const int ngrp = jchunk >> 7;             // groups of 128 j (4 jb)
    const int njb  = jchunk >> 5;             // 32-j blocks

    int st[16];                               // staged raw adj (static idx only)
    auto issue = [&](int g) {
        #pragma unroll
        for (int r = 0; r < 8; ++r) {
            const int* rp = abase + (size_t)r * NN + g * 128;
            st[2 * r]     = rp[0];            // j = g*128 + lane
            st[2 * r + 1] = rp[64];           // j = g*128 + 64 + lane
        }
    };
    auto commit = [&](int buf) {
        #pragma unroll
        for (int r = 0; r < 8; ++r) {
            unsigned long long m0 = __ballot(st[2 * r]     != 0);
            unsigned long long m1 = __ballot(st[2 * r + 1] != 0);
            if (lane == 0) {
                abits[buf][head * 8 + r][0] = (uint32)m0;
                abits[buf][head * 8 + r][1] = (uint32)(m0 >> 32);
                abits[buf][head * 8 + r][2] = (uint32)m1;
                abits[buf][head * 8 + r][3] = (uint32)(m1 >> 32);
            }
        }
    };
    // async B-frag stage: 4x16B per lane, LDS dest = uniform base + lane*16
    auto issueB = [&](int jb, int buf) {
        const unsigned short* hp = hbase + (size_t)jb * (HEADS * 4 * 512);
        #pragma unroll
        for (int f = 0; f < 4; ++f) {
            __builtin_amdgcn_global_load_lds(
                (const void*)(hp + f * 512),
                (void*)&bfB[buf][head][f * 512], 16, 0, 0);
        }
    };

    // prologue: B(0) -> buf0; adj group0 -> st; ballot (auto-drains all); barrier
    issueB(0, 0);
    issue(0);
    commit(0);
    __syncthreads();

    for (int g = 0; g < ngrp; ++g) {
        const int curg = g & 1;
        const bool lastg = (g == ngrp - 1);
        #pragma unroll
        for (int k = 0; k < 4; ++k) {
            const int jb = g * 4 + k;         // local 32-j block
            const int cb = jb & 1;            // bfB read buffer
            // region 1a: dE table loads (issued first: their auto-wait then
            // only drains adj at k==1, not the B pipeline)
            const float* dp  = dEp  + jb * 32;
            const float* dp2 = dE2p + jb * 32;
            f4 alo = *(const f4*)(dp);
            f4 ahi = *(const f4*)(dp + 4);
            f4 blo = *(const f4*)(dp2);
            f4 bhi = *(const f4*)(dp2 + 4);
            __builtin_amdgcn_sched_barrier(0);
            // region 1b: next-jb B-frags into the other LDS buffer
            if (jb + 1 < njb) issueB(jb + 1, cb ^ 1);
            __builtin_amdgcn_sched_barrier(0);
            // region 1c: adj prefetch for next group (k==0 only)
            if (k == 0 && g + 1 < ngrp) issue(g + 1);
            __builtin_amdgcn_sched_barrier(0);
            // wait for THIS jb's B-frags (issued last k); counted, not 0
            if (lastg) {
                asm volatile("s_waitcnt vmcnt(0)" ::: "memory");
            } else if (k <= 1) {
                asm volatile("s_waitcnt vmcnt(24)" ::: "memory");
            } else {
                asm volatile("s_waitcnt vmcnt(8)" ::: "memory");
            }
            __builtin_amdgcn_sched_barrier(0);
            // region 2: compute jb from LDS
            const unsigned short* lb = &bfB[cb][head][lane * 8];
            short8 B0 = *(const short8*)(lb);
            short8 B1 = *(const short8*)(lb + 512);
            short8 B2 = *(const short8*)(lb + 1024);
            short8 B3 = *(const short8*)(lb + 1536);

            uint32 w0 = abits[curg][col][k];
            uint32 w1 = abits[curg][col + 16][k];
            uint32 b0 = (w0 >> (quad * 8)) & 0xFFu;
            uint32 b1 = (w1 >> (quad * 8)) & 0xFFu;
            short8 af0 = build_w(b0, alo, ahi, blo, bhi, es0, es0b);
            short8 af1 = build_w(b1, alo, ahi, blo, bhi, es1, es1b);

            acc[0][0] = __builtin_amdgcn_mfma_f32_16x16x32_bf16(af0, B0, acc[0][0], 0, 0, 0);
            acc[0][1] = __builtin_amdgcn_mfma_f32_16x16x32_bf16(af0, B1, acc[0][1], 0, 0, 0);
            acc[0][2] = __builtin_amdgcn_mfma_f32_16x16x32_bf16(af0, B2, acc[0][2], 0, 0, 0);
            acc[0][3] = __builtin_amdgcn_mfma_f32_16x16x32_bf16(af0, B3, acc[0][3], 0, 0, 0);
            accS[0]   = __builtin_amdgcn_mfma_f32_16x16x32_bf16(af0, ones, accS[0], 0, 0, 0);
            acc[1][0] = __builtin_amdgcn_mfma_f32_16x16x32_bf16(af1, B0, acc[1][0], 0, 0, 0);
            acc[1][1] = __builtin_amdgcn_mfma_f32_16x16x32_bf16(af1, B1, acc[1][1], 0, 0, 0);
            acc[1][2] = __builtin_amdgcn_mfma_f32_16x16x32_bf16(af1, B2, acc[1][2], 0, 0, 0);
            acc[1][3] = __builtin_amdgcn_mfma_f32_16x16x32_bf16(af1, B3, acc[1][3], 0, 0, 0);
            accS[1]   = __builtin_amdgcn_mfma_f32_16x16x32_bf16(af1, ones, accS[1], 0, 0, 0);
        }

        if (g + 1 < ngrp) commit(curg ^ 1);
        __syncthreads();
    }

    // ---- store partials ---------------------------------------------------
    #pragma unroll
    for (int mt = 0; mt < 2; mt++) {
        #pragma unroll
        for (int nt = 0; nt < 4; nt++) {
            #pragma unroll
            for (int r = 0; r < 4; r++) {
                int row = i0 + mt * 16 + quad * 4 + r;
                Pout[((size_t)split * NN + row) * 256 + head * 64 + nt * 16 + col] =
                    acc[mt][nt][r];
            }
        }
        if (col == 0) {
            #pragma unroll
            for (int r = 0; r < 4; r++) {
                int row = i0 + mt * 16 + quad * 4 + r;
                PS[((size_t)split * NN + row) * HEADS + head] = accS[mt][r];
            }
        }
    }
}

// ---------------- K3: reduce splits, normalize, add bias ------------------
__global__ void k3_norm(const float* __restrict__ Pout, const float* __restrict__ PS,
                        const float* __restrict__ bias, float* __restrict__ out,
                        int jsplit)
{
    int t  = blockIdx.x * 256 + threadIdx.x;   // 0..524287
    int c4 = t * 4;
    int i    = c4 >> 8;
    int cb   = c4 & 255;
    int head = cb >> 6;
    f4 num = f4{0.f, 0.f, 0.f, 0.f};
    float den = 0.f;
    for (int s = 0; s < jsplit; s++) {
        num += *(const f4*)(Pout + ((size_t)s * NN + i) * 256 + cb);
        den += PS[((size_t)s * NN + i) * HEADS + head];
    }
    f4 bv = *(const f4*)(bias + cb);
    f4 o  = num * (1.0f / den) + bv;
    *(f4*)(out + c4) = o;
}

extern "C" void kernel_launch(void* const* d_in, const int* in_sizes, int n_in,
                              void* d_out, int out_size, void* d_ws, size_t ws_size,
                              hipStream_t stream) {
    (void)in_sizes; (void)n_in; (void)out_size;
    const float* x    = (const float*)d_in[0];
    const int*   adj  = (const int*)d_in[1];
    const float* W    = (const float*)d_in[2];
    const float* aS   = (const float*)d_in[3];
    const float* aD   = (const float*)d_in[4];
    const float* bias = (const float*)d_in[5];
    float* out = (float*)d_out;

    char* ws = (char*)d_ws;
    unsigned short* WT = (unsigned short*)(ws);              //  128 KB
    unsigned short* hF = (unsigned short*)(ws +   131072);   //  4 MB
    float*  sE   = (float*)(ws +  4325376);                  //  128 KB
    float*  sE2  = (float*)(ws +  4456448);                  //  128 KB
    float*  dE   = (float*)(ws +  4587520);                  //  128 KB
    float*  dE2  = (float*)(ws +  4718592);                  //  128 KB
    float*  PS   = (float*)(ws +  4849664);                  //  up to 1 MB
    float*  Pout = (float*)(ws +  5898240);                  //  jsplit * 8 MB

    const size_t need8 = 5898240ull + 8ull * 8388608ull;
    const int jsplit = (ws_size >= need8) ? 8 : 4;
    const int jshift = (jsplit == 8) ? 3 : 2;
    const int jchunk = NN / jsplit;

    k0_convert<<<256, 256, 0, stream>>>(W, WT);
    k1_hgemm<<<256, 256, 0, stream>>>(x, WT, aS, aD, hF, sE, sE2, dE, dE2);
    k2_gat<<<256 * jsplit, 256, 0, stream>>>(adj, hF, sE, sE2, dE, dE2, Pout, PS, jshift, jchunk);
    k3_norm<<<2048, 256, 0, stream>>>(Pout, PS, bias, out, jsplit);
}